// Round 1
// baseline (158.553 us; speedup 1.0000x reference)
//
#include <hip/hip_runtime.h>

// LengthRegulator: x [B,T,D] f32, dur [B,T] int -> out [B,M,D] f32
// M = out_size / (B*D), data-dependent padded length chosen by the harness.
// idx[b][m] = first j with cumsum(clamp(dur))[j] > m, clipped to T-1.
// Implemented as inverse scatter: token j owns frames [tot[j]-d[j], tot[j]).

#define B_BATCH 32
#define T_TOK   512
#define D_DIM   512
#define DQ      (D_DIM / 4)   // 128 float4 per feature row

__global__ void lr_scan_scatter(const int* __restrict__ dur,
                                int* __restrict__ idx, int M) {
    __shared__ int s[T_TOK];
    const int b = blockIdx.x;
    const int t = threadIdx.x;

    int d = dur[b * T_TOK + t];
    if (d < 0) d = 0;

    // Pre-fill idx row with T-1 (frames beyond the row's total duration).
    for (int m = t; m < M; m += T_TOK) idx[b * M + m] = T_TOK - 1;

    // Inclusive scan (Hillis-Steele) over 512 durations.
    s[t] = d;
    __syncthreads();
    #pragma unroll
    for (int off = 1; off < T_TOK; off <<= 1) {
        int v = (t >= off) ? s[t - off] : 0;
        __syncthreads();
        s[t] += v;
        __syncthreads();
    }
    const int tot = s[t];       // cumsum inclusive at token t
    // Scatter: frames [tot-d, tot) map to token t. tot <= row total <= M.
    for (int p = tot - d; p < tot; ++p) idx[b * M + p] = t;
}

__global__ void lr_gather(const float4* __restrict__ x,
                          const int* __restrict__ idx,
                          float4* __restrict__ out, int M) {
    const int b = blockIdx.y;
    const int e = blockIdx.x * blockDim.x + threadIdx.x;  // float4 index in row-space
    const int QM = M * DQ;
    if (e >= QM) return;
    const int m   = e >> 7;     // e / DQ  (DQ == 128)
    const int q   = e & (DQ - 1);
    const int row = idx[b * M + m];
    out[(size_t)b * QM + e] = x[((size_t)b * T_TOK + row) * DQ + q];
}

extern "C" void kernel_launch(void* const* d_in, const int* in_sizes, int n_in,
                              void* d_out, int out_size, void* d_ws, size_t ws_size,
                              hipStream_t stream) {
    const float* x  = (const float*)d_in[0];
    const int* dur  = (const int*)d_in[1];
    float* out      = (float*)d_out;

    const int M = out_size / (B_BATCH * D_DIM);
    int* idx = (int*)d_ws;   // B * M int32, << ws_size

    lr_scan_scatter<<<B_BATCH, T_TOK, 0, stream>>>(dur, idx, M);

    const int QM = M * DQ;
    dim3 grid((QM + 255) / 256, B_BATCH);
    lr_gather<<<grid, 256, 0, stream>>>((const float4*)x, idx, (float4*)out, M);
}

// Round 2
// 153.710 us; speedup vs baseline: 1.0315x; 1.0315x over previous
//
#include <hip/hip_runtime.h>

// LengthRegulator: x [B,T,D] f32, dur [B,T] int -> out [B,M,D] f32
// M = out_size / (B*D). Semantics (verified vs jnp.searchsorted 'right' + clip):
//   token j owns output rows [cumsum[j]-d[j], cumsum[j]); zero-d tokens own
//   nothing; rows [total, M) are filled with x row T-1.

#define B_BATCH 32
#define T_TOK   512
#define D_DIM   512
#define DQ      (D_DIM / 4)   // 128 float4 per feature row
#define TPB     4             // tokens (rows) per 512-thread block
#define TAILB   32            // tail-fill blocks per batch

// Kernel A: per-batch inclusive scan of clamped durations.
// Writes exclusive start offsets [B,T] and per-batch totals [B] into ws.
__global__ __launch_bounds__(T_TOK)
void lr_scan(const int* __restrict__ dur,
             int* __restrict__ start, int* __restrict__ total) {
    __shared__ int s[T_TOK];
    const int b = blockIdx.x;
    const int t = threadIdx.x;

    int d = dur[b * T_TOK + t];
    if (d < 0) d = 0;

    s[t] = d;
    __syncthreads();
    #pragma unroll
    for (int off = 1; off < T_TOK; off <<= 1) {
        int v = (t >= off) ? s[t - off] : 0;
        __syncthreads();
        s[t] += v;
        __syncthreads();
    }
    const int tot = s[t];                 // inclusive cumsum at token t
    start[b * T_TOK + t] = tot - d;       // exclusive prefix
    if (t == T_TOK - 1) total[b] = tot;   // row total
}

// Kernel B: expansion. Each 128-lane group loads one x row into registers
// and writes it to its d consecutive output rows. Tail blocks fill rows
// [total, M) with x row T-1, strided across TAILB*TPB rows per iteration.
__global__ __launch_bounds__(2 * T_TOK > 512 ? 512 : 512)
void lr_expand(const float4* __restrict__ x,
               const int* __restrict__ dur,
               const int* __restrict__ start,
               const int* __restrict__ total,
               float4* __restrict__ out, int M) {
    const int b   = blockIdx.y;
    const int q   = threadIdx.x & (DQ - 1);   // 0..127 feature-quad
    const int sub = threadIdx.x >> 7;         // 0..TPB-1 row-group in block

    if (blockIdx.x < T_TOK / TPB) {
        const int t = blockIdx.x * TPB + sub;
        int d = dur[b * T_TOK + t];
        if (d <= 0) return;
        const float4 v = x[((size_t)b * T_TOK + t) * DQ + q];
        const int st = start[b * T_TOK + t];
        float4* o = out + ((size_t)b * M + st) * DQ + q;
        for (int k = 0; k < d; ++k) o[k * DQ] = v;
    } else {
        // tail fill: rows [tot, M) <- x row T-1
        const int tot = total[b];
        if (tot >= M) return;
        const float4 v = x[((size_t)b * T_TOK + (T_TOK - 1)) * DQ + q];
        const int j = blockIdx.x - T_TOK / TPB;          // 0..TAILB-1
        for (int r = tot + j * TPB + sub; r < M; r += TAILB * TPB)
            out[((size_t)b * M + r) * DQ + q] = v;
    }
}

extern "C" void kernel_launch(void* const* d_in, const int* in_sizes, int n_in,
                              void* d_out, int out_size, void* d_ws, size_t ws_size,
                              hipStream_t stream) {
    const float* x = (const float*)d_in[0];
    const int* dur = (const int*)d_in[1];
    float* out     = (float*)d_out;

    const int M = out_size / (B_BATCH * D_DIM);

    int* start = (int*)d_ws;               // B*T ints
    int* total = start + B_BATCH * T_TOK;  // B ints

    lr_scan<<<B_BATCH, T_TOK, 0, stream>>>(dur, start, total);

    dim3 grid(T_TOK / TPB + TAILB, B_BATCH);
    lr_expand<<<grid, TPB * DQ, 0, stream>>>((const float4*)x, dur, start, total,
                                             (float4*)out, M);
}